// Round 11
// baseline (933.409 us; speedup 1.0000x reference)
//
#include <hip/hip_runtime.h>
#include <math.h>

#define BATCH 256
#define T 1024
#define IN 19
#define H 128

// tanh via v_exp_f32: tanh(x)=sign(x)*(1-2/(exp(2|x|)+1)); exact to ~1e-7.
__device__ __forceinline__ float fast_tanh(float x) {
    float ax = fabsf(x);
    float e  = __expf(2.0f * ax);
    float r  = 1.0f - 2.0f / (e + 1.0f);
    return copysignf(r, x);
}

// DPP cross-lane move (VALU-only, no LDS pipe).
template <int CTRL>
__device__ __forceinline__ float dppf(float v) {
    return __int_as_float(__builtin_amdgcn_update_dpp(
        0, __float_as_int(v), CTRL, 0xF, 0xF, true));
}
#define XOR1 0xB1   // quad_perm [1,0,3,2]  : lane ^= 1
#define XOR2 0x4E   // quad_perm [2,3,0,1]  : lane ^= 2
#define XOR8 0x128  // row_ror:8            : lane ^= 8 (within 16-lane row)

#define FENCE asm volatile("" ::: "memory")
#define LGKM0 asm volatile("s_waitcnt lgkmcnt(0)" ::: "memory")
#define MAXSPIN (1 << 22)

// Padded LDS offset for hidden unit u: 16-float slices at stride 20.
__device__ __forceinline__ int uoff(int u) { return (u >> 4) * 20 + (u & 15); }

// ---------------------------------------------------------------------------
// Flag-synchronized producer-consumer pipeline. NO per-step s_barrier:
// R5-R10 showed the barrier-per-step structure costs ~650 cyc/step of
// drain+skew that scheduling cannot remove (issue floor ~600, measured 1280).
// 8 waves (512 thr), roles by wave id (SIMD = wave%4):
//   w0,w1 (tid   0..127): L0  = h0_k = tanh(proj_k + Whh0.h0_{k-1})
//   w2,w3 (tid 128..255): B   = B_k  = Wih1.h0_k + b1
//   w4,w5 (tid 256..383): PRJ = proj_k = Wih0.x_k + b0   (runs ahead)
//   w6,w7 (tid 384..511): L1  = h1_t = tanh(B_t + Whh1.h1_{t-1}) + store
// SIMD pairing: {L0,PRJ} x2 (light partner for the chain head), {B,L1} x2.
// Sync: 8-deep LDS rings + per-wave monotonic flag counters. Producer:
// ds_write data; lgkmcnt(0); volatile flag=k+1 (wave-level lgkmcnt covers
// all 64 lanes). Consumer: bounded volatile poll (timeout -> visible fail).
// Deps (acyclic): L0_k <- proj_k, L0_{k-1}, B_{k-8} (ring guard);
// proj_k <- L0_{k-8}; B_k <- L0_k, L1_{k-8}; L1_t <- B_t, L1_{t-1}.
// Single __syncthreads() at init only.
// flags[]: [0]H0a [1]H0b [2]Ba [3]Bb [4]Pa [5]Pb [6]H1a [7]H1b
// ---------------------------------------------------------------------------
__global__ __launch_bounds__(512)
__attribute__((amdgpu_waves_per_eu(2, 2)))
void fused_rnn(const float* __restrict__ x,      // [B,T,IN]
               const float* __restrict__ Wih0,   // [H,IN]
               const float* __restrict__ Whh0,   // [H,H]
               const float* __restrict__ bih0,
               const float* __restrict__ bhh0,
               const float* __restrict__ Wih1,   // [H,H]
               const float* __restrict__ Whh1,   // [H,H]
               const float* __restrict__ bih1,
               const float* __restrict__ bhh1,
               float* __restrict__ out) {        // [B,T,H]
    const int b   = blockIdx.x;
    const int tid = threadIdx.x;

    __shared__ __align__(16) float h0ring[8][160];
    __shared__ __align__(16) float h1ring[8][160];
    __shared__ __align__(16) float Bring[8][H];
    __shared__ __align__(16) float projring[8][H];
    __shared__ __align__(8)  int  flags[8];
    volatile int* vf = (volatile int*)flags;

    if (tid < 8) flags[tid] = 0;
    if (tid < 128) {
        h0ring[7][uoff(tid)] = 0.0f;   // h0_{-1}
        h1ring[7][uoff(tid)] = 0.0f;   // h1_{-1}
    }
    __syncthreads();   // the ONLY barrier

    const int wave = tid >> 6;

    if (wave < 2) {
        // =================== L0 ===================
        __builtin_amdgcn_s_setprio(1);
        const bool b0 = tid & 1, b1 = tid & 2, b2 = tid & 8;
        const int s    = (tid & 3) | ((tid & 8) >> 1);          // slice 0..7
        const int G    = (tid >> 4) * 2 + ((tid >> 2) & 1);     // group 0..15
        const int ub   = G * 8;
        const int ufin = ub + (b0 ? 4 : 0) + (b1 ? 2 : 0) + (b2 ? 1 : 0);
        const int myf  = wave;            // flags[0]/flags[1]

        float wA[8][16];
#pragma unroll
        for (int u = 0; u < 8; ++u) {
            const float* wr = Whh0 + (size_t)(ub + u) * H + s * 16;
#pragma unroll
            for (int c = 0; c < 16; c += 4) {
                float4 v = *(const float4*)&wr[c];
                wA[u][c] = v.x; wA[u][c+1] = v.y; wA[u][c+2] = v.z; wA[u][c+3] = v.w;
            }
        }
        const int so = s * 20;
        const int wo = uoff(ufin);

        for (int ko = 0; ko < T; ko += 8) {
#pragma unroll
            for (int j = 0; j < 8; ++j) {
                const int k = ko + j;
                // wait: proj>=k+1, h0 both>=k (partner exch), B both>=k-7
                {
                    const int np = k + 1, nh = k, nb = k - 7;
                    for (int it = 0; ; ++it) {
                        if (vf[4] >= np && vf[5] >= np &&
                            vf[0] >= nh && vf[1] >= nh &&
                            vf[2] >= nb && vf[3] >= nb) break;
                        if (it >= MAXSPIN) break;
                        __builtin_amdgcn_s_sleep(1);
                    }
                    FENCE;
                }
                float pcur = projring[j][ufin];
                const float* hp = &h0ring[(j + 7) & 7][so];
                float d0=0,d1=0,d2=0,d3=0,d4=0,d5=0,d6=0,d7=0;
#pragma unroll
                for (int c = 0; c < 16; c += 4) {
                    float4 hv = *(const float4*)&hp[c];
                    d0 = fmaf(wA[0][c],hv.x,d0); d0 = fmaf(wA[0][c+1],hv.y,d0); d0 = fmaf(wA[0][c+2],hv.z,d0); d0 = fmaf(wA[0][c+3],hv.w,d0);
                    d1 = fmaf(wA[1][c],hv.x,d1); d1 = fmaf(wA[1][c+1],hv.y,d1); d1 = fmaf(wA[1][c+2],hv.z,d1); d1 = fmaf(wA[1][c+3],hv.w,d1);
                    d2 = fmaf(wA[2][c],hv.x,d2); d2 = fmaf(wA[2][c+1],hv.y,d2); d2 = fmaf(wA[2][c+2],hv.z,d2); d2 = fmaf(wA[2][c+3],hv.w,d2);
                    d3 = fmaf(wA[3][c],hv.x,d3); d3 = fmaf(wA[3][c+1],hv.y,d3); d3 = fmaf(wA[3][c+2],hv.z,d3); d3 = fmaf(wA[3][c+3],hv.w,d3);
                    d4 = fmaf(wA[4][c],hv.x,d4); d4 = fmaf(wA[4][c+1],hv.y,d4); d4 = fmaf(wA[4][c+2],hv.z,d4); d4 = fmaf(wA[4][c+3],hv.w,d4);
                    d5 = fmaf(wA[5][c],hv.x,d5); d5 = fmaf(wA[5][c+1],hv.y,d5); d5 = fmaf(wA[5][c+2],hv.z,d5); d5 = fmaf(wA[5][c+3],hv.w,d5);
                    d6 = fmaf(wA[6][c],hv.x,d6); d6 = fmaf(wA[6][c+1],hv.y,d6); d6 = fmaf(wA[6][c+2],hv.z,d6); d6 = fmaf(wA[6][c+3],hv.w,d6);
                    d7 = fmaf(wA[7][c],hv.x,d7); d7 = fmaf(wA[7][c+1],hv.y,d7); d7 = fmaf(wA[7][c+2],hv.z,d7); d7 = fmaf(wA[7][c+3],hv.w,d7);
                }
                float e0 = (b0 ? d4 : d0) + dppf<XOR1>(b0 ? d0 : d4);
                float e1 = (b0 ? d5 : d1) + dppf<XOR1>(b0 ? d1 : d5);
                float e2 = (b0 ? d6 : d2) + dppf<XOR1>(b0 ? d2 : d6);
                float e3 = (b0 ? d7 : d3) + dppf<XOR1>(b0 ? d3 : d7);
                float g0 = (b1 ? e2 : e0) + dppf<XOR2>(b1 ? e0 : e2);
                float g1 = (b1 ? e3 : e1) + dppf<XOR2>(b1 ? e1 : e3);
                float f  = (b2 ? g1 : g0) + dppf<XOR8>(b2 ? g0 : g1);
                h0ring[j][wo] = fast_tanh(pcur + f);
                LGKM0;
                vf[myf] = k + 1;
                FENCE;
            }
        }
    } else if (wave < 4) {
        // =================== B ===================
        const int p  = tid - 128;
        const bool b0 = p & 1, b1 = p & 2, b2 = p & 8;
        const int s    = (p & 3) | ((p & 8) >> 1);
        const int G    = (p >> 4) * 2 + ((p >> 2) & 1);
        const int ub   = G * 8;
        const int ufin = ub + (b0 ? 4 : 0) + (b1 ? 2 : 0) + (b2 ? 1 : 0);
        const int myf  = 2 + (wave - 2);  // flags[2]/flags[3]

        float wB[8][16];
#pragma unroll
        for (int u = 0; u < 8; ++u) {
            const float* wr = Wih1 + (size_t)(ub + u) * H + s * 16;
#pragma unroll
            for (int c = 0; c < 16; c += 4) {
                float4 v = *(const float4*)&wr[c];
                wB[u][c] = v.x; wB[u][c+1] = v.y; wB[u][c+2] = v.z; wB[u][c+3] = v.w;
            }
        }
        const float biasP = bih1[ufin] + bhh1[ufin];
        const int so = s * 20;

        for (int ko = 0; ko < T; ko += 8) {
#pragma unroll
            for (int j = 0; j < 8; ++j) {
                const int k = ko + j;
                // wait: h0 both>=k+1 (data), L1 both>=k-7 (ring guard)
                {
                    const int nh = k + 1, nl = k - 7;
                    for (int it = 0; ; ++it) {
                        if (vf[0] >= nh && vf[1] >= nh &&
                            vf[6] >= nl && vf[7] >= nl) break;
                        if (it >= MAXSPIN) break;
                        __builtin_amdgcn_s_sleep(1);
                    }
                    FENCE;
                }
                const float* hp = &h0ring[j][so];
                float d0=0,d1=0,d2=0,d3=0,d4=0,d5=0,d6=0,d7=0;
#pragma unroll
                for (int c = 0; c < 16; c += 4) {
                    float4 hv = *(const float4*)&hp[c];
                    d0 = fmaf(wB[0][c],hv.x,d0); d0 = fmaf(wB[0][c+1],hv.y,d0); d0 = fmaf(wB[0][c+2],hv.z,d0); d0 = fmaf(wB[0][c+3],hv.w,d0);
                    d1 = fmaf(wB[1][c],hv.x,d1); d1 = fmaf(wB[1][c+1],hv.y,d1); d1 = fmaf(wB[1][c+2],hv.z,d1); d1 = fmaf(wB[1][c+3],hv.w,d1);
                    d2 = fmaf(wB[2][c],hv.x,d2); d2 = fmaf(wB[2][c+1],hv.y,d2); d2 = fmaf(wB[2][c+2],hv.z,d2); d2 = fmaf(wB[2][c+3],hv.w,d2);
                    d3 = fmaf(wB[3][c],hv.x,d3); d3 = fmaf(wB[3][c+1],hv.y,d3); d3 = fmaf(wB[3][c+2],hv.z,d3); d3 = fmaf(wB[3][c+3],hv.w,d3);
                    d4 = fmaf(wB[4][c],hv.x,d4); d4 = fmaf(wB[4][c+1],hv.y,d4); d4 = fmaf(wB[4][c+2],hv.z,d4); d4 = fmaf(wB[4][c+3],hv.w,d4);
                    d5 = fmaf(wB[5][c],hv.x,d5); d5 = fmaf(wB[5][c+1],hv.y,d5); d5 = fmaf(wB[5][c+2],hv.z,d5); d5 = fmaf(wB[5][c+3],hv.w,d5);
                    d6 = fmaf(wB[6][c],hv.x,d6); d6 = fmaf(wB[6][c+1],hv.y,d6); d6 = fmaf(wB[6][c+2],hv.z,d6); d6 = fmaf(wB[6][c+3],hv.w,d6);
                    d7 = fmaf(wB[7][c],hv.x,d7); d7 = fmaf(wB[7][c+1],hv.y,d7); d7 = fmaf(wB[7][c+2],hv.z,d7); d7 = fmaf(wB[7][c+3],hv.w,d7);
                }
                float e0 = (b0 ? d4 : d0) + dppf<XOR1>(b0 ? d0 : d4);
                float e1 = (b0 ? d5 : d1) + dppf<XOR1>(b0 ? d1 : d5);
                float e2 = (b0 ? d6 : d2) + dppf<XOR1>(b0 ? d2 : d6);
                float e3 = (b0 ? d7 : d3) + dppf<XOR1>(b0 ? d3 : d7);
                float g0 = (b1 ? e2 : e0) + dppf<XOR2>(b1 ? e0 : e2);
                float g1 = (b1 ? e3 : e1) + dppf<XOR2>(b1 ? e1 : e3);
                float f  = (b2 ? g1 : g0) + dppf<XOR8>(b2 ? g0 : g1);
                Bring[j][ufin] = f + biasP;
                LGKM0;
                vf[myf] = k + 1;
                FENCE;
            }
        }
    } else if (wave < 6) {
        // =================== PRJ ===================
        const int q   = tid - 256;        // unit 0..127
        const int myf = 4 + (wave - 4);   // flags[4]/flags[5]

        float wI[IN];
        {
            const float* wr = Wih0 + (size_t)q * IN;
#pragma unroll
            for (int f = 0; f < IN; ++f) wI[f] = wr[f];
        }
        const float bias0 = bih0[q] + bhh0[q];
        const float* xb = x + (size_t)b * T * IN;

        for (int ko = 0; ko < T; ko += 8) {
#pragma unroll
            for (int j = 0; j < 8; ++j) {
                const int k = ko + j;
                // wait: L0 both >= k-7 (ring guard)
                {
                    const int nl = k - 7;
                    for (int it = 0; ; ++it) {
                        if (vf[0] >= nl && vf[1] >= nl) break;
                        if (it >= MAXSPIN) break;
                        __builtin_amdgcn_s_sleep(1);
                    }
                    FENCE;
                }
                const float* xr = xb + (size_t)k * IN;   // uniform row
                float acc = bias0;
#pragma unroll
                for (int f = 0; f < IN; ++f) acc = fmaf(xr[f], wI[f], acc);
                projring[j][q] = acc;
                LGKM0;
                vf[myf] = k + 1;
                FENCE;
            }
        }
    } else {
        // =================== L1 ===================
        __builtin_amdgcn_s_setprio(1);
        const int r  = tid - 384;
        const bool b0 = r & 1, b1 = r & 2, b2 = r & 8;
        const int s    = (r & 3) | ((r & 8) >> 1);
        const int G    = (r >> 4) * 2 + ((r >> 2) & 1);
        const int ub   = G * 8;
        const int ufin = ub + (b0 ? 4 : 0) + (b1 ? 2 : 0) + (b2 ? 1 : 0);
        const int myf  = 6 + (wave - 6);  // flags[6]/flags[7]

        float wA[8][16];
#pragma unroll
        for (int u = 0; u < 8; ++u) {
            const float* wr = Whh1 + (size_t)(ub + u) * H + s * 16;
#pragma unroll
            for (int c = 0; c < 16; c += 4) {
                float4 v = *(const float4*)&wr[c];
                wA[u][c] = v.x; wA[u][c+1] = v.y; wA[u][c+2] = v.z; wA[u][c+3] = v.w;
            }
        }
        float* orow = out + (size_t)b * T * H + ufin;
        const int so = s * 20;
        const int wo = uoff(ufin);

        for (int ko = 0; ko < T; ko += 8) {
#pragma unroll
            for (int j = 0; j < 8; ++j) {
                const int t = ko + j;
                // wait: B both>=t+1 (data), h1 both>=t (partner exch)
                {
                    const int nb = t + 1, nh = t;
                    for (int it = 0; ; ++it) {
                        if (vf[2] >= nb && vf[3] >= nb &&
                            vf[6] >= nh && vf[7] >= nh) break;
                        if (it >= MAXSPIN) break;
                        __builtin_amdgcn_s_sleep(1);
                    }
                    FENCE;
                }
                float Bg = Bring[j][ufin];
                const float* hp = &h1ring[(j + 7) & 7][so];
                float d0=0,d1=0,d2=0,d3=0,d4=0,d5=0,d6=0,d7=0;
#pragma unroll
                for (int c = 0; c < 16; c += 4) {
                    float4 hv = *(const float4*)&hp[c];
                    d0 = fmaf(wA[0][c],hv.x,d0); d0 = fmaf(wA[0][c+1],hv.y,d0); d0 = fmaf(wA[0][c+2],hv.z,d0); d0 = fmaf(wA[0][c+3],hv.w,d0);
                    d1 = fmaf(wA[1][c],hv.x,d1); d1 = fmaf(wA[1][c+1],hv.y,d1); d1 = fmaf(wA[1][c+2],hv.z,d1); d1 = fmaf(wA[1][c+3],hv.w,d1);
                    d2 = fmaf(wA[2][c],hv.x,d2); d2 = fmaf(wA[2][c+1],hv.y,d2); d2 = fmaf(wA[2][c+2],hv.z,d2); d2 = fmaf(wA[2][c+3],hv.w,d2);
                    d3 = fmaf(wA[3][c],hv.x,d3); d3 = fmaf(wA[3][c+1],hv.y,d3); d3 = fmaf(wA[3][c+2],hv.z,d3); d3 = fmaf(wA[3][c+3],hv.w,d3);
                    d4 = fmaf(wA[4][c],hv.x,d4); d4 = fmaf(wA[4][c+1],hv.y,d4); d4 = fmaf(wA[4][c+2],hv.z,d4); d4 = fmaf(wA[4][c+3],hv.w,d4);
                    d5 = fmaf(wA[5][c],hv.x,d5); d5 = fmaf(wA[5][c+1],hv.y,d5); d5 = fmaf(wA[5][c+2],hv.z,d5); d5 = fmaf(wA[5][c+3],hv.w,d5);
                    d6 = fmaf(wA[6][c],hv.x,d6); d6 = fmaf(wA[6][c+1],hv.y,d6); d6 = fmaf(wA[6][c+2],hv.z,d6); d6 = fmaf(wA[6][c+3],hv.w,d6);
                    d7 = fmaf(wA[7][c],hv.x,d7); d7 = fmaf(wA[7][c+1],hv.y,d7); d7 = fmaf(wA[7][c+2],hv.z,d7); d7 = fmaf(wA[7][c+3],hv.w,d7);
                }
                float e0 = (b0 ? d4 : d0) + dppf<XOR1>(b0 ? d0 : d4);
                float e1 = (b0 ? d5 : d1) + dppf<XOR1>(b0 ? d1 : d5);
                float e2 = (b0 ? d6 : d2) + dppf<XOR1>(b0 ? d2 : d6);
                float e3 = (b0 ? d7 : d3) + dppf<XOR1>(b0 ? d3 : d7);
                float g0 = (b1 ? e2 : e0) + dppf<XOR2>(b1 ? e0 : e2);
                float g1 = (b1 ? e3 : e1) + dppf<XOR2>(b1 ? e1 : e3);
                float f  = (b2 ? g1 : g0) + dppf<XOR8>(b2 ? g0 : g1);
                float h1v = fast_tanh(Bg + f);
                h1ring[j][wo] = h1v;
                LGKM0;
                vf[myf] = t + 1;
                FENCE;
                orow[(size_t)t * H] = h1v;   // store off the sync path
            }
        }
    }
}

// ---------------------------------------------------------------------------
extern "C" void kernel_launch(void* const* d_in, const int* in_sizes, int n_in,
                              void* d_out, int out_size, void* d_ws, size_t ws_size,
                              hipStream_t stream) {
    const float* x     = (const float*)d_in[0];
    const float* W_ih0 = (const float*)d_in[1];
    const float* W_hh0 = (const float*)d_in[2];
    const float* b_ih0 = (const float*)d_in[3];
    const float* b_hh0 = (const float*)d_in[4];
    const float* W_ih1 = (const float*)d_in[5];
    const float* W_hh1 = (const float*)d_in[6];
    const float* b_ih1 = (const float*)d_in[7];
    const float* b_hh1 = (const float*)d_in[8];

    float* out = (float*)d_out;

    fused_rnn<<<BATCH, 512, 0, stream>>>(x, W_ih0, W_hh0, b_ih0, b_hh0,
                                         W_ih1, W_hh1, b_ih1, b_hh1, out);
}

// Round 12
// 611.846 us; speedup vs baseline: 1.5256x; 1.5256x over previous
//
#include <hip/hip_runtime.h>
#include <math.h>

#define BATCH 256
#define T 1024
#define IN 19
#define H 128

// tanh via v_exp_f32: tanh(x)=sign(x)*(1-2/(exp(2|x|)+1)); exact to ~1e-7.
__device__ __forceinline__ float fast_tanh(float x) {
    float ax = fabsf(x);
    float e  = __expf(2.0f * ax);
    float r  = 1.0f - 2.0f / (e + 1.0f);
    return copysignf(r, x);
}

// DPP cross-lane move (VALU-only, no LDS pipe).
template <int CTRL>
__device__ __forceinline__ float dppf(float v) {
    return __int_as_float(__builtin_amdgcn_update_dpp(
        0, __float_as_int(v), CTRL, 0xF, 0xF, true));
}
#define XOR1 0xB1   // quad_perm [1,0,3,2]  : lane ^= 1
#define XOR2 0x4E   // quad_perm [2,3,0,1]  : lane ^= 2
#define XOR8 0x128  // row_ror:8            : lane ^= 8 (within 16-lane row)

// Lightweight barrier: waits LDS only (NO vmcnt drain — global loads/stores
// stay in flight across steps). asm memory-clobber pair fences compiler
// code motion on both sides of s_barrier.
__device__ __forceinline__ void sync_fast() {
    asm volatile("s_waitcnt lgkmcnt(0)" ::: "memory");
    __builtin_amdgcn_s_barrier();
    asm volatile("" ::: "memory");
}

// Padded LDS offset for hidden unit u: 16-float slices at stride 20.
__device__ __forceinline__ int uoff(int u) { return (u >> 4) * 20 + (u & 15); }

// ---------------------------------------------------------------------------
// Single fused kernel. 256 blocks x 512 threads (8 waves, 2/SIMD, 1 block/CU).
//   S0 (tid   0..127, 2 waves): h0_k = tanh(proj0_k + Whh0.h0_{k-1})
//   P  (tid 128..383, 4 waves): B_{k-1} = Wih1.h0_{k-1} + b1
//                               waves 4-5 (p>=128) also: proj0_{k+1}
//   S1 (tid 384..511, 2 waves): h1_{k-2} = tanh(B_{k-2} + Whh1.h1_{k-3})
// This is the session's best-measured kernel (R7: 545.9us dispatch). The
// three adjacent structures were all measured worse: deeper pipelining
// (R6 -10%, R10 -5%), LDS flag sync instead of s_barrier (R11 -60%),
// register pinning (R9 null). Step = ~1280 cyc: ~580 VALU-pipe/SIMD +
// ~120 post-barrier LDS latency + ~120 reduce/tanh tail + ~550 barrier
// drain/skew (shown irreducible within this decomposition, R5-R11).
// All groups execute exactly 1027 barriers.
// ---------------------------------------------------------------------------
__global__ __launch_bounds__(512)
__attribute__((amdgpu_waves_per_eu(2, 2)))
void fused_rnn(const float* __restrict__ x,      // [B,T,IN]
               const float* __restrict__ Wih0,   // [H,IN]
               const float* __restrict__ Whh0,   // [H,H]
               const float* __restrict__ bih0,
               const float* __restrict__ bhh0,
               const float* __restrict__ Wih1,   // [H,H]
               const float* __restrict__ Whh1,   // [H,H]
               const float* __restrict__ bih1,
               const float* __restrict__ bhh1,
               float* __restrict__ out) {        // [B,T,H]
    const int b   = blockIdx.x;
    const int tid = threadIdx.x;

    __shared__ __align__(16) float h0ring[4][160];
    __shared__ __align__(16) float h1ring[4][160];
    __shared__ __align__(16) float Bring[4][H];
    __shared__ __align__(16) float projring[4][H];   // proj0 for step k at [k&3]
    // x chunks: 8 steps x 19 floats, stride 20. Chunk c holds rows 8c+1..8c+8.
    __shared__ __align__(16) float xbuf[2][8 * 20];

    if (tid < 128) {
        // =================== S0 (pure recurrence) ===================
        __builtin_amdgcn_s_setprio(1);
        const bool b0 = tid & 1, b1 = tid & 2, b2 = tid & 8;
        const int s    = (tid & 3) | ((tid & 8) >> 1);          // slice 0..7
        const int G    = (tid >> 4) * 2 + ((tid >> 2) & 1);     // group 0..15
        const int ub   = G * 8;
        const int ufin = ub + (b0 ? 4 : 0) + (b1 ? 2 : 0) + (b2 ? 1 : 0);

        float wA[8][16];
#pragma unroll
        for (int u = 0; u < 8; ++u) {
            const float* wr = Whh0 + (size_t)(ub + u) * H + s * 16;
#pragma unroll
            for (int c = 0; c < 16; c += 4) {
                float4 v = *(const float4*)&wr[c];
                wA[u][c] = v.x; wA[u][c+1] = v.y; wA[u][c+2] = v.z; wA[u][c+3] = v.w;
            }
        }
        // prologue: proj_0 self-computed (P's ring starts at proj_1)
        {
            const float* wr = Wih0 + ufin * IN;
            const float* xr = x + (size_t)b * T * IN;   // row 0
            float acc = bih0[ufin] + bhh0[ufin];
#pragma unroll
            for (int f = 0; f < IN; ++f) acc = fmaf(xr[f], wr[f], acc);
            projring[0][ufin] = acc;
        }
        h0ring[3][uoff(ufin)] = 0.0f;   // h0_{-1}
        sync_fast();                     // init barrier

        const int so = s * 20;
        const int wo = uoff(ufin);
        for (int ko = 0; ko < T; ko += 8) {
#pragma unroll
            for (int j = 0; j < 8; ++j) {
                const float* hp = &h0ring[(j + 3) & 3][so];
                float pcur = projring[j & 3][ufin];
                float d0=0,d1=0,d2=0,d3=0,d4=0,d5=0,d6=0,d7=0;
#pragma unroll
                for (int c = 0; c < 16; c += 4) {
                    float4 hv = *(const float4*)&hp[c];
                    d0 = fmaf(wA[0][c],hv.x,d0); d0 = fmaf(wA[0][c+1],hv.y,d0); d0 = fmaf(wA[0][c+2],hv.z,d0); d0 = fmaf(wA[0][c+3],hv.w,d0);
                    d1 = fmaf(wA[1][c],hv.x,d1); d1 = fmaf(wA[1][c+1],hv.y,d1); d1 = fmaf(wA[1][c+2],hv.z,d1); d1 = fmaf(wA[1][c+3],hv.w,d1);
                    d2 = fmaf(wA[2][c],hv.x,d2); d2 = fmaf(wA[2][c+1],hv.y,d2); d2 = fmaf(wA[2][c+2],hv.z,d2); d2 = fmaf(wA[2][c+3],hv.w,d2);
                    d3 = fmaf(wA[3][c],hv.x,d3); d3 = fmaf(wA[3][c+1],hv.y,d3); d3 = fmaf(wA[3][c+2],hv.z,d3); d3 = fmaf(wA[3][c+3],hv.w,d3);
                    d4 = fmaf(wA[4][c],hv.x,d4); d4 = fmaf(wA[4][c+1],hv.y,d4); d4 = fmaf(wA[4][c+2],hv.z,d4); d4 = fmaf(wA[4][c+3],hv.w,d4);
                    d5 = fmaf(wA[5][c],hv.x,d5); d5 = fmaf(wA[5][c+1],hv.y,d5); d5 = fmaf(wA[5][c+2],hv.z,d5); d5 = fmaf(wA[5][c+3],hv.w,d5);
                    d6 = fmaf(wA[6][c],hv.x,d6); d6 = fmaf(wA[6][c+1],hv.y,d6); d6 = fmaf(wA[6][c+2],hv.z,d6); d6 = fmaf(wA[6][c+3],hv.w,d6);
                    d7 = fmaf(wA[7][c],hv.x,d7); d7 = fmaf(wA[7][c+1],hv.y,d7); d7 = fmaf(wA[7][c+2],hv.z,d7); d7 = fmaf(wA[7][c+3],hv.w,d7);
                }
                float e0 = (b0 ? d4 : d0) + dppf<XOR1>(b0 ? d0 : d4);
                float e1 = (b0 ? d5 : d1) + dppf<XOR1>(b0 ? d1 : d5);
                float e2 = (b0 ? d6 : d2) + dppf<XOR1>(b0 ? d2 : d6);
                float e3 = (b0 ? d7 : d3) + dppf<XOR1>(b0 ? d3 : d7);
                float g0 = (b1 ? e2 : e0) + dppf<XOR2>(b1 ? e0 : e2);
                float g1 = (b1 ? e3 : e1) + dppf<XOR2>(b1 ? e1 : e3);
                float f  = (b2 ? g1 : g0) + dppf<XOR8>(b2 ? g0 : g1);
                h0ring[j & 3][wo] = fast_tanh(pcur + f);
                sync_fast();
            }
        }
        sync_fast();   // interval 1024
        sync_fast();   // interval 1025
    } else if (tid < 384) {
        // =================== P (B-projection + layer-0 input projection) ====
        const int p  = tid - 128;
        const bool b0 = p & 1, b1 = p & 2;
        const int s    = (p & 3) | ((p & 8) >> 1);            // slice 0..7
        const int Gp   = (p >> 4) * 2 + ((p >> 2) & 1);       // group 0..31
        const int ub   = Gp * 4;
        const int ufin = ub + (b0 ? 2 : 0) + (b1 ? 1 : 0);

        float wP[4][16];
#pragma unroll
        for (int u = 0; u < 4; ++u) {
            const float* wr = Wih1 + (size_t)(ub + u) * H + s * 16;
#pragma unroll
            for (int c = 0; c < 16; c += 4) {
                float4 v = *(const float4*)&wr[c];
                wP[u][c] = v.x; wP[u][c+1] = v.y; wP[u][c+2] = v.z; wP[u][c+3] = v.w;
            }
        }
        const float biasP = bih1[ufin] + bhh1[ufin];

        // ---- proj duty: waves 4-5 (p>=128), unit = p-128 ----
        const bool hasProj = (p >= 128);
        const int pu = p - 128;                        // proj unit 0..127
        float wIP[20];
        float biasPr = 0.0f;
        const float* xsrc = x + (size_t)b * T * IN + IN;   // row 1 base
        const int idx0  = pu;
        const int idx1  = pu + 128;
        const bool v1   = hasProj && (pu < 24);
        const int slot0 = hasProj ? ((idx0 / IN) * 20 + idx0 % IN) : 0;
        const int slot1 = hasProj ? ((idx1 / IN) * 20 + idx1 % IN) : 0;
        const int XMAX  = (T - 1) * IN - 1;                // last elem rel to xsrc
        float xr0 = 0.0f, xr1 = 0.0f;

        if (hasProj) {
            const float* wr = Wih0 + (size_t)pu * IN;
#pragma unroll
            for (int f = 0; f < IN; ++f) wIP[f] = wr[f];
            wIP[19] = 0.0f;
            biasPr = bih0[pu] + bhh0[pu];
            if (pu < 8) { xbuf[0][pu * 20 + 19] = 0.0f; xbuf[1][pu * 20 + 19] = 0.0f; }
            xbuf[0][slot0] = xsrc[idx0];
            if (v1) xbuf[0][slot1] = xsrc[idx1];
            xr0 = xsrc[152 + idx0];
            if (v1) xr1 = xsrc[152 + idx1];
        }
        sync_fast();   // init barrier

        const int so = s * 20;
        for (int ko = 0; ko < T; ko += 8) {
            const int cb = (ko >> 3) & 1;
#pragma unroll
            for (int j = 0; j < 8; ++j) {
                // ---- B_{k-1}: dot over h0_{k-1} (slot (j+3)&3) ----
                const float* hp = &h0ring[(j + 3) & 3][so];
                float d0=0,d1=0,d2=0,d3=0;
#pragma unroll
                for (int c = 0; c < 16; c += 4) {
                    float4 hv = *(const float4*)&hp[c];
                    d0 = fmaf(wP[0][c],hv.x,d0); d0 = fmaf(wP[0][c+1],hv.y,d0); d0 = fmaf(wP[0][c+2],hv.z,d0); d0 = fmaf(wP[0][c+3],hv.w,d0);
                    d1 = fmaf(wP[1][c],hv.x,d1); d1 = fmaf(wP[1][c+1],hv.y,d1); d1 = fmaf(wP[1][c+2],hv.z,d1); d1 = fmaf(wP[1][c+3],hv.w,d1);
                    d2 = fmaf(wP[2][c],hv.x,d2); d2 = fmaf(wP[2][c+1],hv.y,d2); d2 = fmaf(wP[2][c+2],hv.z,d2); d2 = fmaf(wP[2][c+3],hv.w,d2);
                    d3 = fmaf(wP[3][c],hv.x,d3); d3 = fmaf(wP[3][c+1],hv.y,d3); d3 = fmaf(wP[3][c+2],hv.z,d3); d3 = fmaf(wP[3][c+3],hv.w,d3);
                }
                float e0 = (b0 ? d2 : d0) + dppf<XOR1>(b0 ? d0 : d2);
                float e1 = (b0 ? d3 : d1) + dppf<XOR1>(b0 ? d1 : d3);
                float g  = (b1 ? e1 : e0) + dppf<XOR2>(b1 ? e0 : e1);
                g += dppf<XOR8>(g);
                if (!(p & 8)) Bring[(j + 3) & 3][ufin] = g + biasP;
                // ---- proj0_{k+1} from x row j of current chunk ----
                if (hasProj) {
                    const float* xp = &xbuf[cb][j * 20];
                    float4 xv0 = *(const float4*)&xp[0];
                    float4 xv1 = *(const float4*)&xp[4];
                    float4 xv2 = *(const float4*)&xp[8];
                    float4 xv3 = *(const float4*)&xp[12];
                    float4 xv4 = *(const float4*)&xp[16];   // .w = pad
                    float p0 = biasPr, p1 = 0.0f;
                    p0 = fmaf(xv0.x, wIP[0],  p0); p1 = fmaf(xv0.y, wIP[1],  p1);
                    p0 = fmaf(xv0.z, wIP[2],  p0); p1 = fmaf(xv0.w, wIP[3],  p1);
                    p0 = fmaf(xv1.x, wIP[4],  p0); p1 = fmaf(xv1.y, wIP[5],  p1);
                    p0 = fmaf(xv1.z, wIP[6],  p0); p1 = fmaf(xv1.w, wIP[7],  p1);
                    p0 = fmaf(xv2.x, wIP[8],  p0); p1 = fmaf(xv2.y, wIP[9],  p1);
                    p0 = fmaf(xv2.z, wIP[10], p0); p1 = fmaf(xv2.w, wIP[11], p1);
                    p0 = fmaf(xv3.x, wIP[12], p0); p1 = fmaf(xv3.y, wIP[13], p1);
                    p0 = fmaf(xv3.z, wIP[14], p0); p1 = fmaf(xv3.w, wIP[15], p1);
                    p0 = fmaf(xv4.x, wIP[16], p0); p1 = fmaf(xv4.y, wIP[17], p1);
                    p0 = fmaf(xv4.z, wIP[18], p0); p1 = fmaf(xv4.w, wIP[19], p1);
                    projring[(j + 1) & 3][pu] = p0 + p1;
                    if (j == 7) {
                        // publish chunk c+1 (pre-barrier), fetch chunk c+2
                        float* xd = xbuf[cb ^ 1];
                        xd[slot0] = xr0;
                        if (v1) xd[slot1] = xr1;
                        const int c2 = (ko >> 3) + 2;
                        int o0 = 152 * c2 + idx0; o0 = o0 > XMAX ? XMAX : o0;
                        int o1 = 152 * c2 + idx1; o1 = o1 > XMAX ? XMAX : o1;
                        xr0 = xsrc[o0];
                        if (v1) xr1 = xsrc[o1];
                    }
                }
                sync_fast();
            }
        }
        // ---- epilogue (interval 1024): B_1023 from h0_1023 (slot 3) ----
        {
            const float* hp = &h0ring[3][so];
            float d0=0,d1=0,d2=0,d3=0;
#pragma unroll
            for (int c = 0; c < 16; c += 4) {
                float4 hv = *(const float4*)&hp[c];
                d0 = fmaf(wP[0][c],hv.x,d0); d0 = fmaf(wP[0][c+1],hv.y,d0); d0 = fmaf(wP[0][c+2],hv.z,d0); d0 = fmaf(wP[0][c+3],hv.w,d0);
                d1 = fmaf(wP[1][c],hv.x,d1); d1 = fmaf(wP[1][c+1],hv.y,d1); d1 = fmaf(wP[1][c+2],hv.z,d1); d1 = fmaf(wP[1][c+3],hv.w,d1);
                d2 = fmaf(wP[2][c],hv.x,d2); d2 = fmaf(wP[2][c+1],hv.y,d2); d2 = fmaf(wP[2][c+2],hv.z,d2); d2 = fmaf(wP[2][c+3],hv.w,d2);
                d3 = fmaf(wP[3][c],hv.x,d3); d3 = fmaf(wP[3][c+1],hv.y,d3); d3 = fmaf(wP[3][c+2],hv.z,d3); d3 = fmaf(wP[3][c+3],hv.w,d3);
            }
            float e0 = (b0 ? d2 : d0) + dppf<XOR1>(b0 ? d0 : d2);
            float e1 = (b0 ? d3 : d1) + dppf<XOR1>(b0 ? d1 : d3);
            float g  = (b1 ? e1 : e0) + dppf<XOR2>(b1 ? e0 : e1);
            g += dppf<XOR8>(g);
            if (!(p & 8)) Bring[3][ufin] = g + biasP;
        }
        sync_fast();   // interval 1024
        sync_fast();   // interval 1025
    } else {
        // =================== S1 ===================
        __builtin_amdgcn_s_setprio(1);
        const int w  = tid - 384;
        const bool b0 = w & 1, b1 = w & 2, b2 = w & 8;
        const int s    = (w & 3) | ((w & 8) >> 1);
        const int G    = (w >> 4) * 2 + ((w >> 2) & 1);
        const int ub   = G * 8;
        const int ufin = ub + (b0 ? 4 : 0) + (b1 ? 2 : 0) + (b2 ? 1 : 0);

        float wA[8][16];
#pragma unroll
        for (int u = 0; u < 8; ++u) {
            const float* wr = Whh1 + (size_t)(ub + u) * H + s * 16;
#pragma unroll
            for (int c = 0; c < 16; c += 4) {
                float4 v = *(const float4*)&wr[c];
                wA[u][c] = v.x; wA[u][c+1] = v.y; wA[u][c+2] = v.z; wA[u][c+3] = v.w;
            }
        }
        float* orow = out + (size_t)b * T * H + ufin;
        float sbuf[8];

        h1ring[3][uoff(ufin)] = 0.0f;   // h1_{-1}
        sync_fast();   // init barrier
        sync_fast();   // interval 0
        sync_fast();   // interval 1

        const int so = s * 20;
        const int wo = uoff(ufin);
        for (int ko = 2; ko < 1026; ko += 8) {
#pragma unroll
            for (int j = 0; j < 8; ++j) {
                // ko%8==2: h1_{t-1} slot -> (j+3)&3 ; B_{k-2} slot -> j&3
                const float* hp = &h1ring[(j + 3) & 3][so];
                float Bg = Bring[j & 3][ufin];
                float d0=0,d1=0,d2=0,d3=0,d4=0,d5=0,d6=0,d7=0;
#pragma unroll
                for (int c = 0; c < 16; c += 4) {
                    float4 hv = *(const float4*)&hp[c];
                    d0 = fmaf(wA[0][c],hv.x,d0); d0 = fmaf(wA[0][c+1],hv.y,d0); d0 = fmaf(wA[0][c+2],hv.z,d0); d0 = fmaf(wA[0][c+3],hv.w,d0);
                    d1 = fmaf(wA[1][c],hv.x,d1); d1 = fmaf(wA[1][c+1],hv.y,d1); d1 = fmaf(wA[1][c+2],hv.z,d1); d1 = fmaf(wA[1][c+3],hv.w,d1);
                    d2 = fmaf(wA[2][c],hv.x,d2); d2 = fmaf(wA[2][c+1],hv.y,d2); d2 = fmaf(wA[2][c+2],hv.z,d2); d2 = fmaf(wA[2][c+3],hv.w,d2);
                    d3 = fmaf(wA[3][c],hv.x,d3); d3 = fmaf(wA[3][c+1],hv.y,d3); d3 = fmaf(wA[3][c+2],hv.z,d3); d3 = fmaf(wA[3][c+3],hv.w,d3);
                    d4 = fmaf(wA[4][c],hv.x,d4); d4 = fmaf(wA[4][c+1],hv.y,d4); d4 = fmaf(wA[4][c+2],hv.z,d4); d4 = fmaf(wA[4][c+3],hv.w,d4);
                    d5 = fmaf(wA[5][c],hv.x,d5); d5 = fmaf(wA[5][c+1],hv.y,d5); d5 = fmaf(wA[5][c+2],hv.z,d5); d5 = fmaf(wA[5][c+3],hv.w,d5);
                    d6 = fmaf(wA[6][c],hv.x,d6); d6 = fmaf(wA[6][c+1],hv.y,d6); d6 = fmaf(wA[6][c+2],hv.z,d6); d6 = fmaf(wA[6][c+3],hv.w,d6);
                    d7 = fmaf(wA[7][c],hv.x,d7); d7 = fmaf(wA[7][c+1],hv.y,d7); d7 = fmaf(wA[7][c+2],hv.z,d7); d7 = fmaf(wA[7][c+3],hv.w,d7);
                }
                float e0 = (b0 ? d4 : d0) + dppf<XOR1>(b0 ? d0 : d4);
                float e1 = (b0 ? d5 : d1) + dppf<XOR1>(b0 ? d1 : d5);
                float e2 = (b0 ? d6 : d2) + dppf<XOR1>(b0 ? d2 : d6);
                float e3 = (b0 ? d7 : d3) + dppf<XOR1>(b0 ? d3 : d7);
                float g0 = (b1 ? e2 : e0) + dppf<XOR2>(b1 ? e0 : e2);
                float g1 = (b1 ? e3 : e1) + dppf<XOR2>(b1 ? e1 : e3);
                float f  = (b2 ? g1 : g0) + dppf<XOR8>(b2 ? g0 : g1);
                float h1v = fast_tanh(Bg + f);
                h1ring[j & 3][wo] = h1v;
                sbuf[j] = h1v;
                if (j == 7) {                  // burst-write t = ko-2 .. ko+5
                    const int t0 = ko - 2;
#pragma unroll
                    for (int i = 0; i < 8; ++i)
                        orow[(size_t)(t0 + i) * H] = sbuf[i];
                }
                sync_fast();
            }
        }
        // no trailing barriers needed for S1 (last interval is 1025)
    }
}

// ---------------------------------------------------------------------------
extern "C" void kernel_launch(void* const* d_in, const int* in_sizes, int n_in,
                              void* d_out, int out_size, void* d_ws, size_t ws_size,
                              hipStream_t stream) {
    const float* x     = (const float*)d_in[0];
    const float* W_ih0 = (const float*)d_in[1];
    const float* W_hh0 = (const float*)d_in[2];
    const float* b_ih0 = (const float*)d_in[3];
    const float* b_hh0 = (const float*)d_in[4];
    const float* W_ih1 = (const float*)d_in[5];
    const float* W_hh1 = (const float*)d_in[6];
    const float* b_ih1 = (const float*)d_in[7];
    const float* b_hh1 = (const float*)d_in[8];

    float* out = (float*)d_out;

    fused_rnn<<<BATCH, 512, 0, stream>>>(x, W_ih0, W_hh0, b_ih0, b_hh0,
                                         W_ih1, W_hh1, b_ih1, b_hh1, out);
}